// Round 8
// baseline (547.972 us; speedup 1.0000x reference)
//
#include <hip/hip_runtime.h>
#include <hip/hip_bf16.h>

#define TT 1024
#define DM 256
#define BCN 32

typedef __attribute__((ext_vector_type(8))) short short8;
typedef __attribute__((ext_vector_type(4))) short short4v;
typedef __attribute__((ext_vector_type(4))) float f32x4;

__device__ __forceinline__ void wg_barrier_lds() {
  asm volatile("s_waitcnt lgkmcnt(0)\n\ts_barrier" ::: "memory");
}

__device__ __forceinline__ short bf16b(float f) {
  __hip_bfloat16 h = __float2bfloat16(f);
  return *(short*)&h;
}

// Direct global->LDS DMA (no VGPR round trip, tracked by vmcnt).
__device__ __forceinline__ void dma16(void* l, const void* g) {
  __builtin_amdgcn_global_load_lds(
      (const __attribute__((address_space(1))) void*)g,
      (__attribute__((address_space(3))) void*)l, 16, 0, 0);
}
__device__ __forceinline__ void dma4(void* l, const void* g) {
  __builtin_amdgcn_global_load_lds(
      (const __attribute__((address_space(1))) void*)g,
      (__attribute__((address_space(3))) void*)l, 4, 0, 0);
}

// ---------------------------------------------------------------------------
// Kernel 0: prepack weights fp32 -> bf16 (each element converted exactly
// once; removes per-block cvt work from qkv/proj). 64 blocks x 256 thr.
// ---------------------------------------------------------------------------
__global__ __launch_bounds__(256) void prepack_kernel(
    const float* __restrict__ wq, const float* __restrict__ wo,
    __hip_bfloat16* __restrict__ wqb, __hip_bfloat16* __restrict__ wob)
{
  const int t = blockIdx.x * 256 + threadIdx.x;  // 0..16383
#pragma unroll
  for (int i = 0; i < 4; ++i) {
    const int idx = t + i * 16384;  // 0..65535 float4 chunks
    float4 f;
    __hip_bfloat16* dst;
    int di;
    if (idx < 49152) { f = ((const float4*)wq)[idx]; dst = wqb; di = idx; }
    else { f = ((const float4*)wo)[idx - 49152]; dst = wob; di = idx - 49152; }
    short4v pk;
    pk[0] = bf16b(f.x); pk[1] = bf16b(f.y);
    pk[2] = bf16b(f.z); pk[3] = bf16b(f.w);
    *(short4v*)&dst[di * 4] = pk;
  }
}

// ---------------------------------------------------------------------------
// Kernel 1 (fused): blocks 0..511 = QKV projection; 512..767 = mask bitpack.
// QKV: Xs staged once (33.8 KB LDS -> 4 blocks/CU); X fragments held in
// registers; W fragments read directly from global bf16 (L1/L2-resident,
// all blocks read the same 384 KB). NO per-iter barriers.
// Mask: __ballot over coalesced int reads -> two 32-bit words per ballot.
// Q stored (bc,t,d); K stored with 16B-chunk swizzle ch^(t&7); V stored
// tiled [bc][kb][e][t32]; mask bits [bc][j][q].
// ---------------------------------------------------------------------------
__global__ __launch_bounds__(256) __attribute__((amdgpu_waves_per_eu(4, 4)))
void qkv_kernel(const float* __restrict__ x,
                const __hip_bfloat16* __restrict__ wqb,
                const float* __restrict__ b_qkv, const int* __restrict__ mask,
                __hip_bfloat16* __restrict__ Qb, __hip_bfloat16* __restrict__ Kb,
                __hip_bfloat16* __restrict__ Vtb, unsigned* __restrict__ mbits)
{
  const int tid = threadIdx.x;
  const int w = tid >> 6, l = tid & 63, quad = l >> 4, lm = l & 15;

  if (blockIdx.x >= 512) {  // ---- mask bitpack via ballot ----
    const int b = blockIdx.x - 512;  // 0..255
    const int bc = b >> 3;
    const int q0 = (b & 7) * 128 + w * 32;
    const int* base = mask + (size_t)bc * TT * TT;
    for (int qi = 0; qi < 32; ++qi) {
      const int q = q0 + qi;
      const int* row = base + (size_t)q * TT + l;
#pragma unroll
      for (int j2 = 0; j2 < 16; ++j2) {
        const int v = row[j2 * 64];
        const unsigned long long bal = __ballot(v != 0);
        if (l == 0)
          mbits[((size_t)bc * 32 + j2 * 2) * 1024 + q] = (unsigned)bal;
        if (l == 32)
          mbits[((size_t)bc * 32 + j2 * 2 + 1) * 1024 + q] = (unsigned)(bal >> 32);
      }
    }
    return;
  }

  // ---- qkv blocks ----
  const int tt = blockIdx.x & 15, bc = blockIdx.x >> 4;
  const int t0 = tt * 64;

  __shared__ __attribute__((aligned(16))) __hip_bfloat16 Xs[64][264];  // [t][d]
  const float* xbc = x + (size_t)bc * DM * TT;

  // transpose-stage Xs[t][d] = x[d][t0+t]: 4x4 register transpose, b64 writes
  {
    const int t4 = (tid & 15) * 4;
    for (int s = 0; s < 4; ++s) {
      const int d4 = (tid >> 4) * 4 + s * 64;
      f32x4 f[4];
#pragma unroll
      for (int r = 0; r < 4; ++r)
        f[r] = *(const f32x4*)(xbc + (size_t)(d4 + r) * TT + t0 + t4);
#pragma unroll
      for (int r = 0; r < 4; ++r) {
        short4v pk;
#pragma unroll
        for (int c = 0; c < 4; ++c) pk[c] = bf16b(f[c][r]);
        *(short4v*)&Xs[t4 + r][d4] = pk;
      }
    }
  }
  __syncthreads();

  // X fragments live in registers for the whole e-loop (B or A operand)
  short8 xf[8];
#pragma unroll
  for (int ks = 0; ks < 8; ++ks)
    xf[ks] = *(const short8*)&Xs[w * 16 + lm][ks * 32 + quad * 8];

#pragma unroll 1
  for (int et = 0; et < 12; ++et) {
    const int e0 = et * 64;
    const bool vmode = (et >= 8);
    f32x4 acc[4] = {};
#pragma unroll
    for (int ks = 0; ks < 8; ++ks) {
#pragma unroll
      for (int nt = 0; nt < 4; ++nt) {
        const short8 wb = *(const short8*)(wqb +
            (size_t)(e0 + nt * 16 + lm) * DM + ks * 32 + quad * 8);
        // Q/K: D[e][t] (A=W,B=X); V: D[t][e] (A=X,B=W)
        acc[nt] = vmode
            ? __builtin_amdgcn_mfma_f32_16x16x32_bf16(xf[ks], wb, acc[nt], 0, 0, 0)
            : __builtin_amdgcn_mfma_f32_16x16x32_bf16(wb, xf[ks], acc[nt], 0, 0, 0);
      }
    }

    if (et < 4) {
      // Q: lane t fixed, e consecutive
      const int t = t0 + w * 16 + lm;
#pragma unroll
      for (int nt = 0; nt < 4; ++nt) {
        const int ebase = e0 + nt * 16 + quad * 4;  // 0..255
        short4v pk;
#pragma unroll
        for (int r = 0; r < 4; ++r) pk[r] = bf16b(acc[nt][r] + b_qkv[ebase + r]);
        *(short4v*)&Qb[((size_t)bc * TT + t) * DM + ebase] = pk;
      }
    } else if (!vmode) {
      // K: swizzled chunk ch -> ch^(t&7)
      const int t = t0 + w * 16 + lm;
#pragma unroll
      for (int nt = 0; nt < 4; ++nt) {
        const int eg = e0 + nt * 16 + quad * 4;  // 256..511
        const int eK = eg - 256;
        short4v pk;
#pragma unroll
        for (int r = 0; r < 4; ++r) pk[r] = bf16b(acc[nt][r] + b_qkv[eg + r]);
        const int ch = eK >> 3;
        const int off = (((ch ^ (t & 7)) << 3) | (eK & 7));
        *(short4v*)&Kb[((size_t)bc * TT + t) * DM + off] = pk;
      }
    } else {
      // V tiled: [bc][kb][e][t32], lane e fixed, t consecutive
      const int tb = w * 16 + quad * 4;
      const int kb = tt * 2 + (tb >> 5), tloc = tb & 31;
#pragma unroll
      for (int nt = 0; nt < 4; ++nt) {
        const int e = (e0 - 512) + nt * 16 + lm;
        const float bq = b_qkv[512 + e];
        short4v pk;
#pragma unroll
        for (int r = 0; r < 4; ++r) pk[r] = bf16b(acc[nt][r] + bq);
        *(short4v*)&Vtb[(((size_t)bc * 32 + kb) * 256 + e) * 32 + tloc] = pk;
      }
    }
  }
}

// ---------------------------------------------------------------------------
// Kernel 2: flash attention (unchanged from R7 — global_load_lds dbuf,
// vmcnt(9) pipeline, S^T/O^T operand order, fixed-max softmax, XCD swizzle).
// ---------------------------------------------------------------------------
__global__ __launch_bounds__(256, 2) void attn_kernel(
    const __hip_bfloat16* __restrict__ Qb, const __hip_bfloat16* __restrict__ Kb,
    const __hip_bfloat16* __restrict__ Vtb, const unsigned* __restrict__ Mbits,
    __hip_bfloat16* __restrict__ Ob)
{
  const int fid = blockIdx.x;
  const int xcd = fid & 7, slot = fid >> 3;
  const int bc = xcd * 4 + (slot >> 4);
  const int qt = slot & 15;
  const int q0 = qt * 64;

  __shared__ __attribute__((aligned(16))) __hip_bfloat16 Ks[2][32 * 256];
  __shared__ __attribute__((aligned(16))) __hip_bfloat16 Vs[2][256 * 32];
  __shared__ __attribute__((aligned(16))) __hip_bfloat16 Ps[64][40];
  __shared__ unsigned Msb[2][64];

  const int tid = threadIdx.x, w = tid >> 6, l = tid & 63;
  const int quad = l >> 4, lm = l & 15, lm7 = lm & 7;

  const __hip_bfloat16* Qg =
      Qb + ((size_t)bc * TT + q0 + w * 16 + lm) * DM + quad * 8;
  short8 qf[8];
#pragma unroll
  for (int ks = 0; ks < 8; ++ks) qf[ks] = *(const short8*)(Qg + ks * 32);

  const char* KgT = (const char*)(Kb + (size_t)bc * TT * DM);
  const char* VgT = (const char*)(Vtb + (size_t)bc * TT * DM);
  const unsigned* MgT = Mbits + ((size_t)bc * 32) * 1024 + q0;

  short8 ones;
#pragma unroll
  for (int i = 0; i < 8; ++i) ones[i] = (short)0x3F80;

  f32x4 Oa[16] = {};
  f32x4 Ol = {};

  auto issue = [&](int j, int buf) {
    const char* kg = KgT + (size_t)j * 16384 + w * 4096 + l * 16;
    const char* vg = VgT + (size_t)j * 16384 + w * 4096 + l * 16;
    char* kl = (char*)&Ks[buf][0] + w * 4096;
    char* vl = (char*)&Vs[buf][0] + w * 4096;
#pragma unroll
    for (int i = 0; i < 4; ++i) dma16(kl + i * 1024, kg + i * 1024);
#pragma unroll
    for (int i = 0; i < 4; ++i) dma16(vl + i * 1024, vg + i * 1024);
    dma4(&Msb[buf][0], MgT + (size_t)j * 1024 + l);
  };

  auto compute = [&](int buf) {
    const __hip_bfloat16* KT = &Ks[buf][0];
    const __hip_bfloat16* VT = &Vs[buf][0];
    f32x4 Sa0 = {}, Sa1 = {};
#pragma unroll
    for (int ks = 0; ks < 8; ++ks) {
      const int c = ((ks * 4 + quad) ^ lm7) << 3;
      const short8 a0 = *(const short8*)&KT[lm * 256 + c];
      const short8 a1 = *(const short8*)&KT[(lm + 16) * 256 + c];
      Sa0 = __builtin_amdgcn_mfma_f32_16x16x32_bf16(a0, qf[ks], Sa0, 0, 0, 0);
      Sa1 = __builtin_amdgcn_mfma_f32_16x16x32_bf16(a1, qf[ks], Sa1, 0, 0, 0);
    }
    const unsigned mw = Msb[buf][w * 16 + lm];
#pragma unroll
    for (int nt = 0; nt < 2; ++nt) {
      const f32x4 Sa = nt ? Sa1 : Sa0;
      short4v pk;
#pragma unroll
      for (int r = 0; r < 4; ++r) {
        const int jj = nt * 16 + quad * 4 + r;
        const float p = ((mw >> jj) & 1u)
                            ? 0.f
                            : __expf(fmaf(Sa[r], 0.0625f, -8.0f));
        pk[r] = bf16b(p);
      }
      *(short4v*)&Ps[w * 16 + lm][nt * 16 + quad * 4] = pk;
    }
    const short8 pf = *(const short8*)&Ps[w * 16 + lm][quad * 8];
#pragma unroll
    for (int ct = 0; ct < 16; ++ct) {
      const short8 a = *(const short8*)&VT[(ct * 16 + lm) * 32 + quad * 8];
      Oa[ct] = __builtin_amdgcn_mfma_f32_16x16x32_bf16(a, pf, Oa[ct], 0, 0, 0);
    }
    Ol = __builtin_amdgcn_mfma_f32_16x16x32_bf16(ones, pf, Ol, 0, 0, 0);
  };

  issue(0, 0);
  issue(1, 1);
#pragma unroll 1
  for (int j = 0; j < 32; ++j) {
    const int buf = j & 1;
    if (j < 31)
      asm volatile("s_waitcnt vmcnt(9)" ::: "memory");
    else
      asm volatile("s_waitcnt vmcnt(0)" ::: "memory");
    asm volatile("s_barrier" ::: "memory");
    compute(buf);
    wg_barrier_lds();
    if (j < 30) issue(j + 2, buf);
  }

  const float inv = 1.0f / Ol[0];
  __hip_bfloat16* Og = Ob + ((size_t)bc * TT + q0 + w * 16 + lm) * DM;
#pragma unroll
  for (int ct = 0; ct < 16; ++ct) {
    short4v pk;
#pragma unroll
    for (int r = 0; r < 4; ++r) pk[r] = bf16b(Oa[ct][r] * inv);
    *(short4v*)&Og[ct * 16 + quad * 4] = pk;
  }
}

// ---------------------------------------------------------------------------
// Kernel 3: output projection. O tile staged once (33.8 KB -> 4 blocks/CU);
// O fragments in registers; W_out bf16 fragments direct from global.
// Loops 4 f-tiles, no per-tile barrier. grid 512 (16 tt x 32 bc).
// ---------------------------------------------------------------------------
__global__ __launch_bounds__(256) __attribute__((amdgpu_waves_per_eu(4, 4)))
void proj_kernel(const __hip_bfloat16* __restrict__ Ob,
                 const __hip_bfloat16* __restrict__ wob,
                 const float* __restrict__ b_out, float* __restrict__ out)
{
  const int tt = blockIdx.x & 15, bc = blockIdx.x >> 4;
  const int t0 = tt * 64;

  __shared__ __attribute__((aligned(16))) __hip_bfloat16 As[64][264];

  const int tid = threadIdx.x;
  const int w = tid >> 6, l = tid & 63, quad = l >> 4, lm = l & 15;

  const uint4* Og4 = (const uint4*)(Ob + ((size_t)bc * TT + t0) * DM);
#pragma unroll
  for (int i = 0; i < 8; ++i) {
    const int chunk = tid + i * 256, row = chunk >> 5, c8 = chunk & 31;
    *(uint4*)&As[row][c8 * 8] = Og4[chunk];
  }
  __syncthreads();

  short8 of[8];  // O fragments (B operand, col t = w*16+lm)
#pragma unroll
  for (int ks = 0; ks < 8; ++ks)
    of[ks] = *(const short8*)&As[w * 16 + lm][ks * 32 + quad * 8];

#pragma unroll 1
  for (int ft = 0; ft < 4; ++ft) {
    const int f0 = ft * 64;
    f32x4 acc[4] = {};
#pragma unroll
    for (int ks = 0; ks < 8; ++ks) {
#pragma unroll
      for (int nt = 0; nt < 4; ++nt) {
        const short8 wa = *(const short8*)(wob +
            (size_t)(f0 + nt * 16 + lm) * DM + ks * 32 + quad * 8);
        acc[nt] = __builtin_amdgcn_mfma_f32_16x16x32_bf16(wa, of[ks], acc[nt], 0, 0, 0);
      }
    }
    const int t = t0 + w * 16 + lm;
#pragma unroll
    for (int nt = 0; nt < 4; ++nt) {
      const int fb = f0 + nt * 16 + quad * 4;
      float4 o;
      o.x = acc[nt][0] + b_out[fb + 0];
      o.y = acc[nt][1] + b_out[fb + 1];
      o.z = acc[nt][2] + b_out[fb + 2];
      o.w = acc[nt][3] + b_out[fb + 3];
      *(float4*)&out[((size_t)bc * TT + t) * DM + fb] = o;
    }
  }
}

// ---------------------------------------------------------------------------
extern "C" void kernel_launch(void* const* d_in, const int* in_sizes, int n_in,
                              void* d_out, int out_size, void* d_ws, size_t ws_size,
                              hipStream_t stream) {
  const float* x = (const float*)d_in[0];
  const int* mask = (const int*)d_in[1];
  const float* w_qkv = (const float*)d_in[2];
  const float* b_qkv = (const float*)d_in[3];
  const float* w_out = (const float*)d_in[4];
  const float* b_out = (const float*)d_in[5];
  float* out = (float*)d_out;

  const size_t N = (size_t)BCN * TT * DM;
  __hip_bfloat16* Qb  = (__hip_bfloat16*)d_ws;   // 16.8 MB (reused as O)
  __hip_bfloat16* Kb  = Qb + N;                  // 16.8 MB, swizzled rows
  __hip_bfloat16* Vtb = Kb + N;                  // 16.8 MB, 16 KB tiles
  unsigned* Mbits     = (unsigned*)(Vtb + N);    // 4 MB, [bc][j][q]
  __hip_bfloat16* wqb = (__hip_bfloat16*)(Mbits + (1u << 20));  // 384 KB
  __hip_bfloat16* wob = wqb + 768 * 256;         // 128 KB

  prepack_kernel<<<dim3(64), dim3(256), 0, stream>>>(w_qkv, w_out, wqb, wob);
  qkv_kernel<<<dim3(768), dim3(256), 0, stream>>>(x, wqb, b_qkv, mask,
                                                  Qb, Kb, Vtb, Mbits);
  attn_kernel<<<dim3(512), dim3(256), 0, stream>>>(Qb, Kb, Vtb, Mbits, Qb);
  proj_kernel<<<dim3(512), dim3(256), 0, stream>>>(Qb, wob, b_out, out);
}